// Round 2
// 567.467 us; speedup vs baseline: 1.0049x; 1.0049x over previous
//
#include <hip/hip_runtime.h>
#include <hip/hip_bf16.h>
#include <math.h>

typedef __bf16 bf16x8 __attribute__((ext_vector_type(8)));
typedef __bf16 bf16x2 __attribute__((ext_vector_type(2)));
typedef float  f32x4  __attribute__((ext_vector_type(4)));

#define CI_STRIDE 262144   // 64*64*64
#define B_STRIDE  16777216 // 64*CI_STRIDE
#define Z2 68              // z' extent (64 + 2 halo each side)
#define CP 40              // padded ci-half leading dim (32 data + 8 pad; 80 B rows)
#define NROW 12            // 8 data y-rows + 2 halo each side

// ---------------------------------------------------------------------------
// Kernel 1: bf16 weights, layout Wb[t][h][co][ci32]  (h = ci-half).
// Folds 0.1 conv scale, ALPHA factors, cos(pi d)/5^1.5, sh1; center tap t=62
// absorbs the block-diagonal pointwise mix sc (0.25*lin_w).
// ---------------------------------------------------------------------------
__global__ __launch_bounds__(256) void gen_w(const float* __restrict__ tp,
                                             const float* __restrict__ lw0,
                                             const float* __restrict__ lw1,
                                             __bf16* __restrict__ Wb) {
    const int t  = blockIdx.x;            // tap id 0..124, t = dx*25+dy*5+dz
    const int dx = t / 25, dy = (t / 5) % 5, dz = t % 5;
    const float rx = -1.f + 0.5f * (float)dx;
    const float ry = -1.f + 0.5f * (float)dy;
    const float rz = -1.f + 0.5f * (float)dz;
    const float d    = sqrtf(rx * rx + ry * ry + rz * rz);
    const float invd = (d > 0.f) ? (1.f / d) : 0.f;
    const float SQRT3 = 1.7320508075688772f;
    const float sh1_0 = SQRT3 * ry * invd;   // sh1 = sqrt(3)*unit[[1,2,0]]
    const float sh1_1 = SQRT3 * rz * invd;
    const float sh1_2 = SQRT3 * rx * invd;
    float basis[5];
#pragma unroll
    for (int m = 0; m < 5; ++m) {
        float u = (d - 0.25f * (float)m) * 4.0f;
        basis[m] = expf(-u * u) * (1.0f / 1.12f);
    }
    const float S  = cosf(3.14159265358979323846f * d) * (1.0f / 11.180339887498949f);
    const float fA = 0.1f * 0.17677669529663687f * S;
    const float fB = 0.1f * 0.3061862178478972f * 0.5773502691896258f * S;
    const float fC = 0.1f * 0.17677669529663687f * 0.5773502691896258f * S;
    const float fD = fB;

    for (int e = threadIdx.x; e < 4096; e += 256) {
        const int co = e >> 6, ci = e & 63;
        int   tt;
        float f;
        if (ci < 16) {
            if (co < 16) { tt = ci * 16 + co; f = fA; }
            else {
                const int c = co - 16, w = c / 3, kk = c % 3;
                tt = 256 + ci * 16 + w;
                f  = fB * ((kk == 0) ? sh1_0 : (kk == 1) ? sh1_1 : sh1_2);
            }
        } else {
            const int a = ci - 16, uu = a / 3, ii = a % 3;
            const float s1i = (ii == 0) ? sh1_0 : (ii == 1) ? sh1_1 : sh1_2;
            if (co < 16) { tt = 768 + uu * 16 + co; f = fC * s1i; }
            else {
                const int c = co - 16, w = c / 3, kk = c % 3;
                tt = 512 + uu * 16 + w;
                f  = (ii == kk) ? fD : 0.0f;
            }
        }
        float E = 0.f;
#pragma unroll
        for (int m = 0; m < 5; ++m) E += basis[m] * tp[m * 1024 + tt];
        float val = f * E;
        if (t == 62) {  // fold sc into the center tap
            if (ci < 16 && co < 16) {
                val += 0.25f * lw0[ci * 16 + co];
            } else if (ci >= 16 && co >= 16) {
                const int a = co - 16, bq = ci - 16;
                const int wq = a / 3, iq = a % 3, uq = bq / 3, iiq = bq % 3;
                if (iq == iiq) val += 0.25f * lw1[uq * 16 + wq];
            }
        }
        // layout: Wb[((t*2 + h)*64 + co)*32 + ci_lo]
        Wb[((size_t)(t * 2 + (ci >> 5)) * 64 + co) * 32 + (ci & 31)] = (__bf16)val;
    }
}

// ---------------------------------------------------------------------------
// Kernel 2: implicit-GEMM conv. Block = 256 thr (4 waves) = (b, x, 8-y grp).
// LDS 65,280 B -> 2 blocks resident per CU: one block's plane staging
// overlaps the other block's MFMA stream (the 1-block version stalled the
// whole CU at every staging barrier -> MfmaUtil 58%).
// Wave w: 2 y-rows (2w, 2w+1), M=64 co x N=128 (2y x 64z), K split in two
// ci-32 passes. A-fragments register-prefetched one tap ahead from global.
// Staging writes are ds_write_b128 (bf16x8): with CP=40 (20-dword rows) the
// old per-dword writes hit only 8 banks (8-way conflict, 3.3e7 cycles);
// b128 writes cover all 32 banks exactly 2x = hardware minimum.
// ---------------------------------------------------------------------------
__global__ __launch_bounds__(256, 2) void conv_mfma(const float* __restrict__ x,
                                                    const __bf16* __restrict__ Wb,
                                                    float* __restrict__ out) {
    __shared__ __align__(16) __bf16 xs[NROW * Z2 * CP];   // 65,280 B
    const int tid = threadIdx.x;
    const int l = tid & 63, w = tid >> 6;     // 4 waves
    const int q = l >> 4, i16 = l & 15;
    const int b  = blockIdx.x >> 9;
    const int xc = (blockIdx.x >> 3) & 63;
    const int y0 = (blockIdx.x & 7) << 3;

    f32x4 acc[4][8];
#pragma unroll
    for (int mt = 0; mt < 4; ++mt)
#pragma unroll
        for (int nt = 0; nt < 8; ++nt) acc[mt][nt] = (f32x4)(0.f);

    // zero the z-halo columns z' in {0,1,66,67}, ci 0..31 (staging never
    // writes them; values persist across all planes)
    if (tid < NROW * 4 * 4) {
        const int r = tid >> 4, rem = tid & 15;
        const int zs = rem >> 2, c8 = (rem & 3) << 3;
        const int zp = (zs < 2) ? zs : (64 + zs);
        bf16x8 zz = {(__bf16)0.f, (__bf16)0.f, (__bf16)0.f, (__bf16)0.f,
                     (__bf16)0.f, (__bf16)0.f, (__bf16)0.f, (__bf16)0.f};
        *(bf16x8*)(xs + ((size_t)r * Z2 + zp) * CP + c8) = zz;
    }

    const float* xb = x + (size_t)b * B_STRIDE;

    // preload A-fragments for s=0 (h=0, t=0): co = mt*16+i16, k = q*8+j
    bf16x8 Acur[4], Anext[4];
#pragma unroll
    for (int mt = 0; mt < 4; ++mt)
        Acur[mt] = *(const bf16x8*)(Wb + ((size_t)(mt * 16 + i16)) * 32 + q * 8);

    for (int h = 0; h < 2; ++h) {
        for (int dx = 0; dx < 5; ++dx) {
            __syncthreads();   // all waves done reading the previous plane
            {   // stage plane x' = xc+dx-2, rows y' = y0-2 .. y0+9, ci-half h
                const int xp = xc + dx - 2;
                const bool xok = (xp >= 0) && (xp < 64);
                for (int r = w; r < NROW; r += 4) {
                    const int yp = y0 + r - 2;
                    const bool ok = xok && (yp >= 0) && (yp < 64);
                    const float* src = xb + (size_t)(h * 32) * CI_STRIDE
                                     + (size_t)xp * 4096 + yp * 64 + l;
                    __bf16* dst = xs + ((size_t)r * Z2 + 2 + l) * CP;
                    if (ok) {
#pragma unroll
                        for (int c0 = 0; c0 < 32; c0 += 8) {
                            bf16x8 pk;
#pragma unroll
                            for (int j = 0; j < 8; ++j)
                                pk[j] = (__bf16)src[(size_t)(c0 + j) * CI_STRIDE];
                            *(bf16x8*)(dst + c0) = pk;   // ds_write_b128
                        }
                    } else {
                        bf16x8 zz = {(__bf16)0.f, (__bf16)0.f, (__bf16)0.f, (__bf16)0.f,
                                     (__bf16)0.f, (__bf16)0.f, (__bf16)0.f, (__bf16)0.f};
#pragma unroll
                        for (int c0 = 0; c0 < 32; c0 += 8) *(bf16x8*)(dst + c0) = zz;
                    }
                }
            }
            __syncthreads();

            for (int dydz = 0; dydz < 25; ++dydz) {
                const int t = dx * 25 + dydz;
                const int s = h * 125 + t;
                // prefetch A for s+1 (sequence: h-major, t ascending)
                {
                    const int sn = (s < 249) ? (s + 1) : s;
                    const int hn = sn / 125, tn = sn % 125;
                    const __bf16* wp = Wb + ((size_t)(tn * 2 + hn) * 64 + i16) * 32 + q * 8;
#pragma unroll
                    for (int mt = 0; mt < 4; ++mt)
                        Anext[mt] = *(const bf16x8*)(wp + (size_t)mt * 16 * 32);
                }
                const int dy = dydz / 5, dz = dydz % 5;
                const __bf16* bbase = xs + ((size_t)(2 * w + dy) * Z2 + dz + i16) * CP + q * 8;
                bf16x8 Bf[8];
#pragma unroll
                for (int yy = 0; yy < 2; ++yy)
#pragma unroll
                    for (int zt = 0; zt < 4; ++zt)
                        Bf[yy * 4 + zt] = *(const bf16x8*)(bbase + (size_t)(yy * Z2 + zt * 16) * CP);
                __builtin_amdgcn_s_setprio(1);
#pragma unroll
                for (int mt = 0; mt < 4; ++mt)
#pragma unroll
                    for (int nt = 0; nt < 8; ++nt)
                        acc[mt][nt] = __builtin_amdgcn_mfma_f32_16x16x32_bf16(
                            Acur[mt], Bf[nt], acc[mt][nt], 0, 0, 0);
                __builtin_amdgcn_s_setprio(0);
#pragma unroll
                for (int mt = 0; mt < 4; ++mt) Acur[mt] = Anext[mt];
            }
        }
    }

    // epilogue: D layout col(n)=lane&15, row(m)=q*4+j
    const size_t ob = (size_t)b * B_STRIDE + (size_t)xc * 4096;
#pragma unroll
    for (int mt = 0; mt < 4; ++mt)
#pragma unroll
        for (int j = 0; j < 4; ++j) {
            const int co = mt * 16 + q * 4 + j;
            float* op = out + ob + (size_t)co * CI_STRIDE;
#pragma unroll
            for (int nt = 0; nt < 8; ++nt) {
                const int y = y0 + 2 * w + (nt >> 2);
                const int z = (nt & 3) * 16 + i16;
                op[y * 64 + z] = acc[mt][nt][j];
            }
        }
}

extern "C" void kernel_launch(void* const* d_in, const int* in_sizes, int n_in,
                              void* d_out, int out_size, void* d_ws, size_t ws_size,
                              hipStream_t stream) {
    (void)in_sizes; (void)n_in; (void)out_size; (void)ws_size;
    const float* x   = (const float*)d_in[0];  // (2, 64, 64, 64, 64) fp32
    const float* lw0 = (const float*)d_in[1];  // (16, 16)
    const float* lw1 = (const float*)d_in[2];  // (16, 16)
    const float* tp  = (const float*)d_in[3];  // (5, 1024)
    float* out = (float*)d_out;
    __bf16* Wb = (__bf16*)d_ws;                // 125*2*64*32*2 B = 1.0 MB

    gen_w<<<125, 256, 0, stream>>>(tp, lw0, lw1, Wb);
    conv_mfma<<<1024, 256, 0, stream>>>(x, Wb, out);
}

// Round 3
// 566.457 us; speedup vs baseline: 1.0067x; 1.0018x over previous
//
#include <hip/hip_runtime.h>
#include <hip/hip_bf16.h>
#include <math.h>

typedef __bf16 bf16x8 __attribute__((ext_vector_type(8)));
typedef __bf16 bf16x2 __attribute__((ext_vector_type(2)));
typedef float  f32x4  __attribute__((ext_vector_type(4)));

#define CI_STRIDE 262144   // 64*64*64
#define B_STRIDE  16777216 // 64*CI_STRIDE
#define Z2 68              // z' extent (64 + 2 halo each side)
#define CP 40              // padded ci-half leading dim (32 data + 8 pad; 80 B rows)
#define NROW 12            // 8 data y-rows + 2 halo each side

// ---------------------------------------------------------------------------
// Kernel 1: bf16 weights, layout Wb[t][h][co][ci32]  (h = ci-half).
// Folds 0.1 conv scale, ALPHA factors, cos(pi d)/5^1.5, sh1; center tap t=62
// absorbs the block-diagonal pointwise mix sc (0.25*lin_w).
// ---------------------------------------------------------------------------
__global__ __launch_bounds__(256) void gen_w(const float* __restrict__ tp,
                                             const float* __restrict__ lw0,
                                             const float* __restrict__ lw1,
                                             __bf16* __restrict__ Wb) {
    const int t  = blockIdx.x;            // tap id 0..124, t = dx*25+dy*5+dz
    const int dx = t / 25, dy = (t / 5) % 5, dz = t % 5;
    const float rx = -1.f + 0.5f * (float)dx;
    const float ry = -1.f + 0.5f * (float)dy;
    const float rz = -1.f + 0.5f * (float)dz;
    const float d    = sqrtf(rx * rx + ry * ry + rz * rz);
    const float invd = (d > 0.f) ? (1.f / d) : 0.f;
    const float SQRT3 = 1.7320508075688772f;
    const float sh1_0 = SQRT3 * ry * invd;   // sh1 = sqrt(3)*unit[[1,2,0]]
    const float sh1_1 = SQRT3 * rz * invd;
    const float sh1_2 = SQRT3 * rx * invd;
    float basis[5];
#pragma unroll
    for (int m = 0; m < 5; ++m) {
        float u = (d - 0.25f * (float)m) * 4.0f;
        basis[m] = expf(-u * u) * (1.0f / 1.12f);
    }
    const float S  = cosf(3.14159265358979323846f * d) * (1.0f / 11.180339887498949f);
    const float fA = 0.1f * 0.17677669529663687f * S;
    const float fB = 0.1f * 0.3061862178478972f * 0.5773502691896258f * S;
    const float fC = 0.1f * 0.17677669529663687f * 0.5773502691896258f * S;
    const float fD = fB;

    for (int e = threadIdx.x; e < 4096; e += 256) {
        const int co = e >> 6, ci = e & 63;
        int   tt;
        float f;
        if (ci < 16) {
            if (co < 16) { tt = ci * 16 + co; f = fA; }
            else {
                const int c = co - 16, w = c / 3, kk = c % 3;
                tt = 256 + ci * 16 + w;
                f  = fB * ((kk == 0) ? sh1_0 : (kk == 1) ? sh1_1 : sh1_2);
            }
        } else {
            const int a = ci - 16, uu = a / 3, ii = a % 3;
            const float s1i = (ii == 0) ? sh1_0 : (ii == 1) ? sh1_1 : sh1_2;
            if (co < 16) { tt = 768 + uu * 16 + co; f = fC * s1i; }
            else {
                const int c = co - 16, w = c / 3, kk = c % 3;
                tt = 512 + uu * 16 + w;
                f  = (ii == kk) ? fD : 0.0f;
            }
        }
        float E = 0.f;
#pragma unroll
        for (int m = 0; m < 5; ++m) E += basis[m] * tp[m * 1024 + tt];
        float val = f * E;
        if (t == 62) {  // fold sc into the center tap
            if (ci < 16 && co < 16) {
                val += 0.25f * lw0[ci * 16 + co];
            } else if (ci >= 16 && co >= 16) {
                const int a = co - 16, bq = ci - 16;
                const int wq = a / 3, iq = a % 3, uq = bq / 3, iiq = bq % 3;
                if (iq == iiq) val += 0.25f * lw1[uq * 16 + wq];
            }
        }
        // layout: Wb[((t*2 + h)*64 + co)*32 + ci_lo]
        Wb[((size_t)(t * 2 + (ci >> 5)) * 64 + co) * 32 + (ci & 31)] = (__bf16)val;
    }
}

// ---------------------------------------------------------------------------
// Kernel 2: implicit-GEMM conv. Block = 256 thr (4 waves) = (b, x, 8-y grp).
// 65,280 B LDS -> 2 blocks/CU. Per tap, BOTH operands are register-prefetched
// one tap ahead: A (weights) from global, B (activation frags) from LDS.
// Without B-prefetch every tap was [8 ds_read_b128 -> lgkmcnt(0) -> 32 MFMA]:
// both waves of a SIMD finish MFMA together, then both stall ~200cy on LDS
// latency with the matrix pipe dark (MfmaUtil 61%). Prefetching B for t+1
// during t's MFMAs turns the drain into a counted lgkmcnt wait.
// No prefetch across the staging barrier (buffer is overwritten); each plane
// preloads tap 0 after the barrier instead.
// ---------------------------------------------------------------------------
__global__ __launch_bounds__(256, 2) void conv_mfma(const float* __restrict__ x,
                                                    const __bf16* __restrict__ Wb,
                                                    float* __restrict__ out) {
    __shared__ __align__(16) __bf16 xs[NROW * Z2 * CP];   // 65,280 B
    const int tid = threadIdx.x;
    const int l = tid & 63, w = tid >> 6;     // 4 waves
    const int q = l >> 4, i16 = l & 15;
    const int b  = blockIdx.x >> 9;
    const int xc = (blockIdx.x >> 3) & 63;
    const int y0 = (blockIdx.x & 7) << 3;

    f32x4 acc[4][8];
#pragma unroll
    for (int mt = 0; mt < 4; ++mt)
#pragma unroll
        for (int nt = 0; nt < 8; ++nt) acc[mt][nt] = (f32x4)(0.f);

    // zero the z-halo columns z' in {0,1,66,67}, ci 0..31 (staging never
    // writes them; values persist across all planes)
    if (tid < NROW * 4 * 4) {
        const int r = tid >> 4, rem = tid & 15;
        const int zs = rem >> 2, c8 = (rem & 3) << 3;
        const int zp = (zs < 2) ? zs : (64 + zs);
        bf16x8 zz = {(__bf16)0.f, (__bf16)0.f, (__bf16)0.f, (__bf16)0.f,
                     (__bf16)0.f, (__bf16)0.f, (__bf16)0.f, (__bf16)0.f};
        *(bf16x8*)(xs + ((size_t)r * Z2 + zp) * CP + c8) = zz;
    }

    const float* xb = x + (size_t)b * B_STRIDE;

    // preload A-fragments for s=0 (h=0, t=0): co = mt*16+i16, k = q*8+j
    bf16x8 Acur[4], Anext[4];
#pragma unroll
    for (int mt = 0; mt < 4; ++mt)
        Acur[mt] = *(const bf16x8*)(Wb + ((size_t)(mt * 16 + i16)) * 32 + q * 8);

    for (int h = 0; h < 2; ++h) {
        for (int dx = 0; dx < 5; ++dx) {
            __syncthreads();   // all waves done reading the previous plane
            {   // stage plane x' = xc+dx-2, rows y' = y0-2 .. y0+9, ci-half h
                const int xp = xc + dx - 2;
                const bool xok = (xp >= 0) && (xp < 64);
                for (int r = w; r < NROW; r += 4) {
                    const int yp = y0 + r - 2;
                    const bool ok = xok && (yp >= 0) && (yp < 64);
                    const float* src = xb + (size_t)(h * 32) * CI_STRIDE
                                     + (size_t)xp * 4096 + yp * 64 + l;
                    __bf16* dst = xs + ((size_t)r * Z2 + 2 + l) * CP;
                    if (ok) {
#pragma unroll
                        for (int c0 = 0; c0 < 32; c0 += 8) {
                            bf16x8 pk;
#pragma unroll
                            for (int j = 0; j < 8; ++j)
                                pk[j] = (__bf16)src[(size_t)(c0 + j) * CI_STRIDE];
                            *(bf16x8*)(dst + c0) = pk;   // ds_write_b128
                        }
                    } else {
                        bf16x8 zz = {(__bf16)0.f, (__bf16)0.f, (__bf16)0.f, (__bf16)0.f,
                                     (__bf16)0.f, (__bf16)0.f, (__bf16)0.f, (__bf16)0.f};
#pragma unroll
                        for (int c0 = 0; c0 < 32; c0 += 8) *(bf16x8*)(dst + c0) = zz;
                    }
                }
            }
            __syncthreads();

            // preload B fragments for tap (dy=0, dz=0) of this plane
            bf16x8 Bf[8], Bn[8];
            {
                const __bf16* bb0 = xs + ((size_t)(2 * w) * Z2 + i16) * CP + q * 8;
#pragma unroll
                for (int yy = 0; yy < 2; ++yy)
#pragma unroll
                    for (int zt = 0; zt < 4; ++zt)
                        Bf[yy * 4 + zt] = *(const bf16x8*)(bb0 + (size_t)(yy * Z2 + zt * 16) * CP);
            }

            for (int dydz = 0; dydz < 25; ++dydz) {
                const int t = dx * 25 + dydz;
                const int s = h * 125 + t;
                // prefetch B for the next tap of this plane (never across barrier)
                if (dydz < 24) {
                    const int dy2 = (dydz + 1) / 5, dz2 = (dydz + 1) % 5;
                    const __bf16* bb = xs + ((size_t)(2 * w + dy2) * Z2 + dz2 + i16) * CP + q * 8;
#pragma unroll
                    for (int yy = 0; yy < 2; ++yy)
#pragma unroll
                        for (int zt = 0; zt < 4; ++zt)
                            Bn[yy * 4 + zt] = *(const bf16x8*)(bb + (size_t)(yy * Z2 + zt * 16) * CP);
                }
                // prefetch A for s+1 (sequence: h-major, t ascending)
                {
                    const int sn = (s < 249) ? (s + 1) : s;
                    const int hn = sn / 125, tn = sn % 125;
                    const __bf16* wp = Wb + ((size_t)(tn * 2 + hn) * 64 + i16) * 32 + q * 8;
#pragma unroll
                    for (int mt = 0; mt < 4; ++mt)
                        Anext[mt] = *(const bf16x8*)(wp + (size_t)mt * 16 * 32);
                }
                __builtin_amdgcn_s_setprio(1);
#pragma unroll
                for (int mt = 0; mt < 4; ++mt)
#pragma unroll
                    for (int nt = 0; nt < 8; ++nt)
                        acc[mt][nt] = __builtin_amdgcn_mfma_f32_16x16x32_bf16(
                            Acur[mt], Bf[nt], acc[mt][nt], 0, 0, 0);
                __builtin_amdgcn_s_setprio(0);
#pragma unroll
                for (int mt = 0; mt < 4; ++mt) Acur[mt] = Anext[mt];
                if (dydz < 24) {
#pragma unroll
                    for (int k = 0; k < 8; ++k) Bf[k] = Bn[k];
                }
            }
        }
    }

    // epilogue: D layout col(n)=lane&15, row(m)=q*4+j
    const size_t ob = (size_t)b * B_STRIDE + (size_t)xc * 4096;
#pragma unroll
    for (int mt = 0; mt < 4; ++mt)
#pragma unroll
        for (int j = 0; j < 4; ++j) {
            const int co = mt * 16 + q * 4 + j;
            float* op = out + ob + (size_t)co * CI_STRIDE;
#pragma unroll
            for (int nt = 0; nt < 8; ++nt) {
                const int y = y0 + 2 * w + (nt >> 2);
                const int z = (nt & 3) * 16 + i16;
                op[y * 64 + z] = acc[mt][nt][j];
            }
        }
}

extern "C" void kernel_launch(void* const* d_in, const int* in_sizes, int n_in,
                              void* d_out, int out_size, void* d_ws, size_t ws_size,
                              hipStream_t stream) {
    (void)in_sizes; (void)n_in; (void)out_size; (void)ws_size;
    const float* x   = (const float*)d_in[0];  // (2, 64, 64, 64, 64) fp32
    const float* lw0 = (const float*)d_in[1];  // (16, 16)
    const float* lw1 = (const float*)d_in[2];  // (16, 16)
    const float* tp  = (const float*)d_in[3];  // (5, 1024)
    float* out = (float*)d_out;
    __bf16* Wb = (__bf16*)d_ws;                // 125*2*64*32*2 B = 1.0 MB

    gen_w<<<125, 256, 0, stream>>>(tp, lw0, lw1, Wb);
    conv_mfma<<<1024, 256, 0, stream>>>(x, Wb, out);
}